// Round 8
// baseline (223.541 us; speedup 1.0000x reference)
//
#include <hip/hip_runtime.h>

// Problem constants
#define B_   2
#define S_   2048
#define H_   2048
#define NH_  16
#define G_   4
#define HD_  128
#define KV_  512
#define HQKV 3072   // fused Q|K|V output width

typedef __attribute__((ext_vector_type(8))) short bf16x8;
typedef __attribute__((ext_vector_type(4))) float f32x4;

__device__ __forceinline__ unsigned short f2bf(float f) {
    unsigned u = __float_as_uint(f);
    u += 0x7fff + ((u >> 16) & 1);   // RNE
    return (unsigned short)(u >> 16);
}
__device__ __forceinline__ float bf2f(unsigned short s) {
    return __uint_as_float(((unsigned)s) << 16);
}
// D.lo = bf16(a), D.hi = bf16(b)  (RNE)
__device__ __forceinline__ unsigned cvtpk(float a, float b) {
    unsigned r;
    asm volatile("v_cvt_pk_bf16_f32 %0, %1, %2" : "=v"(r) : "v"(a), "v"(b));
    return r;
}

#define GLDS16(gsrc, ldst)                                                            \
    __builtin_amdgcn_global_load_lds(                                                 \
        (const __attribute__((address_space(1))) void*)(gsrc),                        \
        (__attribute__((address_space(3))) void*)(ldst), 16, 0, 0)

// 1/sqrt(128) * log2(e): folded into Q columns of the QKV GEMM epilogue
#define SC2F (0.08838834764831843f * 1.4426950408889634f)

// ---------------- fp32 -> bf16 elementwise ----------------
__global__ void k_cvt_bf16(const float* __restrict__ in, unsigned short* __restrict__ out, int n4) {
    int i = blockIdx.x * blockDim.x + threadIdx.x;
    if (i >= n4) return;
    float4 v = ((const float4*)in)[i];
    ushort4 o;
    o.x = f2bf(v.x); o.y = f2bf(v.y); o.z = f2bf(v.z); o.w = f2bf(v.w);
    ((ushort4*)out)[i] = o;
}

// ---------------- fp32 [R][C] -> bf16 [C][R] (weight transpose+convert) ----------------
__global__ void k_transpose_cvt(const float* __restrict__ in, unsigned short* __restrict__ out,
                                int R, int C) {
    __shared__ float t[32][33];
    int c0 = blockIdx.x * 32, r0 = blockIdx.y * 32;
    int tx = threadIdx.x, ty = threadIdx.y;   // 32 x 8
#pragma unroll
    for (int i = 0; i < 4; ++i)
        t[ty + i*8][tx] = in[(size_t)(r0 + ty + i*8) * C + c0 + tx];
    __syncthreads();
#pragma unroll
    for (int i = 0; i < 4; ++i)
        out[(size_t)(c0 + ty + i*8) * R + r0 + tx] = f2bf(t[tx][ty + i*8]);
}

// ---------------- fused Wq|Wk|Wv transpose+convert -> WqkvT [3072][2048] ----------------
__global__ void k_transpose_qkv(const float* __restrict__ Wq, const float* __restrict__ Wk,
                                const float* __restrict__ Wv, unsigned short* __restrict__ out) {
    __shared__ float t[32][33];
    int n0g = blockIdx.x * 32;               // output row block (0..3071)
    int h0 = blockIdx.y * 32;                // input row block (0..2047)
    const float* src; int C, n0l;
    if (n0g < H_)            { src = Wq; C = H_;  n0l = n0g; }
    else if (n0g < H_ + KV_) { src = Wk; C = KV_; n0l = n0g - H_; }
    else                     { src = Wv; C = KV_; n0l = n0g - H_ - KV_; }
    int tx = threadIdx.x, ty = threadIdx.y;  // 32 x 8
#pragma unroll
    for (int i = 0; i < 4; ++i)
        t[ty + i*8][tx] = src[(size_t)(h0 + ty + i*8) * C + n0l + tx];
    __syncthreads();
#pragma unroll
    for (int i = 0; i < 4; ++i)
        out[(size_t)(n0g + ty + i*8) * H_ + h0 + tx] = f2bf(t[tx][ty + i*8]);
}

// ---------------- concat bq|bk|bv -> [3072] ----------------
__global__ void k_concat_bias(const float* __restrict__ bq, const float* __restrict__ bk,
                              const float* __restrict__ bv, float* __restrict__ out) {
    int i = blockIdx.x * 256 + threadIdx.x;
    if (i >= HQKV) return;
    out[i] = (i < H_) ? bq[i] : (i < H_ + KV_ ? bk[i - H_] : bv[i - H_ - KV_]);
}

// ---------------- V slice of QKV [B*S][3072] -> V^T [B][KV][S] ----------------
__global__ void k_transpose_v(const unsigned short* __restrict__ in, unsigned short* __restrict__ out) {
    __shared__ unsigned short t[32][33];
    int b = blockIdx.z;
    int c0 = blockIdx.x * 32, s0 = blockIdx.y * 32;
    int tx = threadIdx.x, ty = threadIdx.y;
#pragma unroll
    for (int i = 0; i < 4; ++i)
        t[ty + i*8][tx] = in[((size_t)b * S_ + s0 + ty + i*8) * HQKV + (H_ + KV_) + c0 + tx];
    __syncthreads();
#pragma unroll
    for (int i = 0; i < 4; ++i)
        out[((size_t)b * KV_ + c0 + ty + i*8) * S_ + s0 + tx] = t[tx][ty + i*8];
}

// ---------------- pipelined bf16 GEMM: C[M,N] = A[M,K] * Bt[N,K]^T + bias ----------------
// 128x128 tile, BK=64, double-buffered LDS (64 KB -> 2 blocks/CU), depth-2 counted
// prefetch: stage tile t+2 after the end barrier; vmcnt(8) at top keeps tile t+1's
// loads in flight across both barriers (full K-tile of latency hiding). 4-phase
// compute (one frag-row each) with setprio around MFMA. XCD-chunked block swizzle.
// Ledger (per wave, 8 GLDS/tile): prologue S0,S1 -> out=16. iter t: vmcnt(8) retires
// oldest tile (t); compute; barrier; stage t+2 -> out<=16. Last iter: vmcnt(0).
template <bool BF16OUT, bool QSCALE>
__global__ __launch_bounds__(256) void k_gemm_bt(
    const unsigned short* __restrict__ A, const unsigned short* __restrict__ Bt,
    const float* __restrict__ bias, void* __restrict__ Cout, int M, int N, int K, int nbx) {
    __shared__ __align__(16) unsigned short As[2][128 * 64];
    __shared__ __align__(16) unsigned short Bs[2][128 * 64];
    const int tid = threadIdx.x, lane = tid & 63, w = tid >> 6;
    const int l15 = lane & 15, l4 = lane >> 4;
    const int wr = w >> 1, wc = w & 1;
    // XCD-chunked swizzle (nwg % 8 == 0): each XCD gets consecutive wg -> shared B-panels
    const int nwg = nbx * ((gridDim.x) / nbx);  // == gridDim.x
    const int cpx = gridDim.x >> 3;
    const int wg = (blockIdx.x & 7) * cpx + (blockIdx.x >> 3);
    const int m0 = (wg % nbx) * 128, n0 = (wg / nbx) * 128;
    (void)nwg;
    f32x4 acc[4][4] = {};

    auto stage = [&](int buf, int kt) {
#pragma unroll
        for (int i = 0; i < 4; ++i) {
            int p = (w * 4 + i) * 64 + lane;
            int row = p >> 3, c = (p & 7) ^ (row & 7);
            GLDS16(A + (size_t)(m0 + row) * K + kt * 64 + c * 8,
                   &As[buf][(w * 4 + i) * 512]);
        }
#pragma unroll
        for (int i = 0; i < 4; ++i) {
            int p = (w * 4 + i) * 64 + lane;
            int row = p >> 3, c = (p & 7) ^ (row & 7);
            GLDS16(Bt + (size_t)(n0 + row) * K + kt * 64 + c * 8,
                   &Bs[buf][(w * 4 + i) * 512]);
        }
    };

    const int NT = K >> 6;
    stage(0, 0);
    if (NT > 1) stage(1, 1);

    for (int t = 0; t < NT; ++t) {
        const int cur = t & 1;
        if (t + 1 < NT) { asm volatile("s_waitcnt vmcnt(8)" ::: "memory"); }
        else            { asm volatile("s_waitcnt vmcnt(0)" ::: "memory"); }
        __builtin_amdgcn_s_barrier();
        __builtin_amdgcn_sched_barrier(0);

        // B-frags once per tile: 4 cols x 2 k-steps
        bf16x8 bfr[2][4];
#pragma unroll
        for (int ks = 0; ks < 2; ++ks)
#pragma unroll
            for (int n = 0; n < 4; ++n) {
                int row = wc * 64 + n * 16 + l15;
                int sl = (ks * 4 + l4) ^ (row & 7);
                bfr[ks][n] = *(const bf16x8*)(&Bs[cur][(row * 8 + sl) * 8]);
            }
        // 4 phases: one frag-row each {2 ds_read -> 8 MFMA}
#pragma unroll
        for (int fr = 0; fr < 4; ++fr) {
            int row = wr * 64 + fr * 16 + l15;
            bf16x8 af0 = *(const bf16x8*)(&As[cur][(row * 8 + (l4 ^ (row & 7))) * 8]);
            bf16x8 af1 = *(const bf16x8*)(&As[cur][(row * 8 + ((4 + l4) ^ (row & 7))) * 8]);
            __builtin_amdgcn_s_setprio(1);
#pragma unroll
            for (int n = 0; n < 4; ++n)
                acc[fr][n] = __builtin_amdgcn_mfma_f32_16x16x32_bf16(af0, bfr[0][n], acc[fr][n], 0, 0, 0);
#pragma unroll
            for (int n = 0; n < 4; ++n)
                acc[fr][n] = __builtin_amdgcn_mfma_f32_16x16x32_bf16(af1, bfr[1][n], acc[fr][n], 0, 0, 0);
            __builtin_amdgcn_s_setprio(0);
        }

        __builtin_amdgcn_s_barrier();       // all waves done reading buf[cur]
        __builtin_amdgcn_sched_barrier(0);
        if (t + 2 < NT) stage(cur, t + 2);  // deep prefetch into freed buffer
    }

#pragma unroll
    for (int fr = 0; fr < 4; ++fr) {
        int row = m0 + wr * 64 + fr * 16 + l4 * 4;
#pragma unroll
        for (int n = 0; n < 4; ++n) {
            int col = n0 + wc * 64 + n * 16 + l15;
            float bv = bias[col];
#pragma unroll
            for (int r = 0; r < 4; ++r) {
                float v = acc[fr][n][r] + bv;
                if (QSCALE) { if (col < H_) v *= SC2F; }
                if (BF16OUT)
                    ((unsigned short*)Cout)[(size_t)(row + r) * N + col] = f2bf(v);
                else
                    ((float*)Cout)[(size_t)(row + r) * N + col] = v;
            }
        }
    }
}

// ---------------- causal GQA flash attention: swapped-QK, in-register softmax ----------------
// s = mfma(K,Q) -> S^T: lane (l15=q, l4) holds k = n*16+l4*4+r  -> softmax row is
// lane-local (15 ops + 2 shfl).  o = mfma(V^T, P^T) -> O^T: col=q matches, rescale is
// lane-scalar.  P^T B-frag built in-register: cvt_pk packs + 16 shfl (no P LDS).
// LDS = K 16KB + V 16KB = 32768 B -> 4-5 blocks/CU. Split-K jobs as R6.
__global__ __launch_bounds__(256, 4) void k_flash(
    const unsigned short* __restrict__ QKV,  // [B*S][3072]  Q|K|V  (Q pre-scaled)
    const unsigned short* __restrict__ VT,   // [B][KV][S]
    unsigned short* __restrict__ Oa,         // [B*S][H]
    unsigned short* __restrict__ part1,      // [512][64][128] bf16 chunk1 partial O
    float* __restrict__ mlbuf) {             // [1024][64][2] f32 (m,l) per chunk
    __shared__ __align__(16) unsigned short Ks[64 * 128];    // K tile, chunk-swizzled
    __shared__ __align__(16) unsigned short Vs[128 * 64];    // V^T tile, chunk-swizzled
    const int tid = threadIdx.x, lane = tid & 63, w = tid >> 6;
    const int l15 = lane & 15, l4 = lane >> 4;
    const int bid = blockIdx.x;               // 0..1535
    const int xcd = bid & 7, idx = bid >> 3;  // 192 jobs per XCD
    const int bh = xcd * 4 + (idx & 3);       // 4 heads per XCD = one (b,g)
    const int jidx = idx >> 2;                // 0..47, descending work
    const int b = bh >> 4, nh = bh & 15, g = nh >> 2;

    int qt, t0, t1, mode;                     // mode: 0 full, 1 chunk0, 2 chunk1
    if (jidx < 16) { qt = 16 + jidx; t0 = 0; t1 = 16; mode = 1; }
    else {
        int k = jidx - 16, j = k >> 1;
        if ((k & 1) == 0) { qt = 31 - j; t0 = 16; t1 = qt + 1; mode = 2; }
        else              { qt = 15 - j; t0 = 0;  t1 = qt + 1; mode = 0; }
    }
    const int qbase = qt * 64 + w * 16;       // wave's 16 q-rows; lane's q = qbase + l15

    const unsigned short* kgbase = QKV + (size_t)b * S_ * HQKV + H_ + g * HD_;
    const unsigned short* vgbase = VT + ((size_t)b * KV_ + g * HD_) * S_;

    auto issueK = [&](int kt) {
        const int kv0 = kt * 64;
#pragma unroll
        for (int i = 0; i < 4; ++i) {
            int p = i * 256 + tid;
            int row = p >> 4, c = (p & 15) ^ (row & 15);
            GLDS16(kgbase + (size_t)(kv0 + row) * HQKV + c * 8, &Ks[(i * 256 + w * 64) * 8]);
        }
    };
    auto issueV = [&](int kt) {
        const int kv0 = kt * 64;
#pragma unroll
        for (int i = 0; i < 4; ++i) {
            int p = i * 256 + tid;
            int row = p >> 3, c = (p & 7) ^ (row & 7);
            GLDS16(vgbase + (size_t)row * S_ + kv0 + c * 8, &Vs[(i * 256 + w * 64) * 8]);
        }
    };

    // Q fragments (already scaled by 1/sqrt(d)*log2e); lane l15 = q-row -> B-frag of QK
    bf16x8 qf[4];
#pragma unroll
    for (int kb = 0; kb < 4; ++kb)
        qf[kb] = *(const bf16x8*)(QKV + (size_t)(b * S_ + qbase + l15) * HQKV +
                                  nh * HD_ + kb * 32 + l4 * 8);

    f32x4 o[8] = {};                          // O^T: o[nc][r] = O[d=nc*16+l4*4+r][q=l15]
    float m_r = -1e30f, l_r = 0.f;            // per-lane (q = l15) running max / sum

    // shfl sources for P^T frag build
    const int src0 = l15 + 16 * ((2 * l4) & 3);
    const int src1 = l15 + 16 * ((2 * l4 + 1) & 3);
    const bool hsel = ((l4 >> 1) & 1) != 0;

    issueK(t0);
    issueV(t0);

    for (int kt = t0; kt < t1; ++kt) {
        const int kv0 = kt * 64;
        // K(kt) landed (issued a full phase ago); V(kt) may still be in flight
        asm volatile("s_waitcnt vmcnt(4)" ::: "memory");
        __builtin_amdgcn_s_barrier();
        __builtin_amdgcn_sched_barrier(0);

        // S^T = K Q^T  (A = K rows, B = Q rows)
        f32x4 s[4] = {};
#pragma unroll
        for (int kb = 0; kb < 4; ++kb) {
            bf16x8 kf[4];
#pragma unroll
            for (int n = 0; n < 4; ++n) {
                int row = n * 16 + l15;
                int sl = (kb * 4 + l4) ^ (row & 15);
                kf[n] = *(const bf16x8*)(&Ks[(row * 16 + sl) * 8]);
            }
            __builtin_amdgcn_s_setprio(1);
#pragma unroll
            for (int n = 0; n < 4; ++n)
                s[n] = __builtin_amdgcn_mfma_f32_16x16x32_bf16(kf[n], qf[kb], s[n], 0, 0, 0);
            __builtin_amdgcn_s_setprio(0);
        }
        // causal mask: kcol = kv0 + n*16 + l4*4 + r,  qrow = qbase + l15
        if (kv0 + 63 > qbase) {
            const int qrow = qbase + l15;
#pragma unroll
            for (int n = 0; n < 4; ++n)
#pragma unroll
                for (int r = 0; r < 4; ++r) {
                    int kcol = kv0 + n * 16 + l4 * 4 + r;
                    if (kcol > qrow) s[n][r] = -1e30f;
                }
        }
        // per-lane softmax over 16 values + 2-shfl group reduce (lanes l15, l15+16,32,48)
        float pmax = s[0][0];
#pragma unroll
        for (int n = 0; n < 4; ++n)
#pragma unroll
            for (int r = 0; r < 4; ++r) pmax = fmaxf(pmax, s[n][r]);
        pmax = fmaxf(pmax, __shfl_xor(pmax, 16));
        pmax = fmaxf(pmax, __shfl_xor(pmax, 32));
        // defer-max (THR=8)
        if (__any(pmax > m_r + 8.0f)) {
            float mn = fmaxf(m_r, pmax);
            float sf = exp2f(m_r - mn);
            m_r = mn;
            l_r *= sf;
#pragma unroll
            for (int nc = 0; nc < 8; ++nc) {
                f32x4 t = o[nc];
                t[0] *= sf; t[1] *= sf; t[2] *= sf; t[3] *= sf;
                o[nc] = t;
            }
        }
        float rsum = 0.f;
#pragma unroll
        for (int n = 0; n < 4; ++n)
#pragma unroll
            for (int r = 0; r < 4; ++r) {
                float p = exp2f(s[n][r] - m_r);
                s[n][r] = p;
                rsum += p;
            }
        rsum += __shfl_xor(rsum, 16);
        rsum += __shfl_xor(rsum, 32);
        l_r += rsum;

        // pack P to bf16 pairs: plo[n] = (r0,r1), phi[n] = (r2,r3)
        unsigned plo[4], phi[4];
#pragma unroll
        for (int n = 0; n < 4; ++n) {
            plo[n] = cvtpk(s[n][0], s[n][1]);
            phi[n] = cvtpk(s[n][2], s[n][3]);
        }

        // V(kt) landed + all waves done reading Ks
        asm volatile("s_waitcnt vmcnt(0)" ::: "memory");
        __builtin_amdgcn_s_barrier();
        __builtin_amdgcn_sched_barrier(0);
        if (kt + 1 < t1) issueK(kt + 1);   // hides under PV + next-phase wait

        // O^T += V^T P^T : per kb build P^T B-frag in-register via shfl, then 8 MFMA
#pragma unroll
        for (int kb = 0; kb < 2; ++kb) {
            const int n0i = 2 * kb, n1i = 2 * kb + 1;
            unsigned a0, a1, w0, w1, w2, w3;
            a0 = __shfl((int)plo[n0i], src0); a1 = __shfl((int)plo[n1i], src0); w0 = hsel ? a1 : a0;
            a0 = __shfl((int)phi[n0i], src0); a1 = __shfl((int)phi[n1i], src0); w1 = hsel ? a1 : a0;
            a0 = __shfl((int)plo[n0i], src1); a1 = __shfl((int)plo[n1i], src1); w2 = hsel ? a1 : a0;
            a0 = __shfl((int)phi[n0i], src1); a1 = __shfl((int)phi[n1i], src1); w3 = hsel ? a1 : a0;
            int4 pw = make_int4((int)w0, (int)w1, (int)w2, (int)w3);
            bf16x8 pf = *(bf16x8*)&pw;
            __builtin_amdgcn_s_setprio(1);
#pragma unroll
            for (int nc = 0; nc < 8; ++nc) {
                int row = nc * 16 + l15;
                int sl = (kb * 4 + l4) ^ (row & 7);
                bf16x8 vf = *(const bf16x8*)(&Vs[(row * 8 + sl) * 8]);
                o[nc] = __builtin_amdgcn_mfma_f32_16x16x32_bf16(vf, pf, o[nc], 0, 0, 0);
            }
            __builtin_amdgcn_s_setprio(0);
        }

        // all waves done reading Vs -> safe to overwrite
        __builtin_amdgcn_s_barrier();
        __builtin_amdgcn_sched_barrier(0);
        if (kt + 1 < t1) issueV(kt + 1);   // hides under next QK^T + softmax
    }

    // epilogue: lane writes q = qbase + l15, d = nc*16 + l4*4 + (0..3) as bf16x4
    const int qrow = qbase + l15;
    if (mode == 0) {
        float inv = 1.0f / l_r;
        size_t base = (size_t)(b * S_ + qrow) * H_ + nh * HD_ + l4 * 4;
#pragma unroll
        for (int nc = 0; nc < 8; ++nc) {
            uint2 pk;
            pk.x = cvtpk(o[nc][0] * inv, o[nc][1] * inv);
            pk.y = cvtpk(o[nc][2] * inv, o[nc][3] * inv);
            *(uint2*)(Oa + base + nc * 16) = pk;
        }
    } else {
        const int base = bh * 16 + (qt - 16);
        const int c = (mode == 1) ? 0 : 1;
        float* mlrec = mlbuf + (size_t)(base * 2 + c) * 64 * 2;
        if (l4 == 0) {
            int row = w * 16 + l15;
            mlrec[row * 2 + 0] = m_r;
            mlrec[row * 2 + 1] = l_r;
        }
        if (mode == 1) {
            size_t ob = (size_t)(b * S_ + qrow) * H_ + nh * HD_ + l4 * 4;
#pragma unroll
            for (int nc = 0; nc < 8; ++nc) {
                uint2 pk;
                pk.x = cvtpk(o[nc][0], o[nc][1]);
                pk.y = cvtpk(o[nc][2], o[nc][3]);
                *(uint2*)(Oa + ob + nc * 16) = pk;
            }
        } else {
            size_t pb = ((size_t)base * 64 + w * 16 + l15) * 128 + l4 * 4;
#pragma unroll
            for (int nc = 0; nc < 8; ++nc) {
                uint2 pk;
                pk.x = cvtpk(o[nc][0], o[nc][1]);
                pk.y = cvtpk(o[nc][2], o[nc][3]);
                *(uint2*)(part1 + pb + nc * 16) = pk;
            }
        }
    }
}

// ---------------- combine split-K partials ----------------
__global__ __launch_bounds__(256) void k_combine(
    const float* __restrict__ mlbuf, const unsigned short* __restrict__ part1,
    unsigned short* __restrict__ Oa) {
    int rec = blockIdx.x;                 // 0..511: bh*16 + (qt-16)
    int bh = rec >> 4, qt = 16 + (rec & 15);
    int b = bh >> 4, nh = bh & 15;
    int row = threadIdx.x >> 2;           // 0..63
    int dseg = (threadIdx.x & 3) * 32;
    const float* ml0 = mlbuf + (size_t)(rec * 2 + 0) * 128;
    const float* ml1 = mlbuf + (size_t)(rec * 2 + 1) * 128;
    float m0 = ml0[row * 2], l0 = ml0[row * 2 + 1];
    float m1 = ml1[row * 2], l1 = ml1[row * 2 + 1];
    float M = fmaxf(m0, m1);
    float a0 = exp2f(m0 - M), a1 = exp2f(m1 - M);
    float L = a0 * l0 + a1 * l1;
    float s0 = a0 / L, s1 = a1 / L;
    size_t ob = ((size_t)(b * S_) + qt * 64 + row) * H_ + nh * HD_ + dseg;
    const unsigned short* p1 = part1 + ((size_t)rec * 64 + row) * 128 + dseg;
#pragma unroll
    for (int i = 0; i < 4; ++i) {
        bf16x8 v0 = *(const bf16x8*)(Oa + ob + i * 8);
        bf16x8 v1 = *(const bf16x8*)(p1 + i * 8);
        bf16x8 oo;
#pragma unroll
        for (int e = 0; e < 8; ++e)
            oo[e] = (short)f2bf(bf2f((unsigned short)v0[e]) * s0 +
                                bf2f((unsigned short)v1[e]) * s1);
        *(bf16x8*)(Oa + ob + i * 8) = oo;
    }
}

// ---------------- launch ----------------
extern "C" void kernel_launch(void* const* d_in, const int* in_sizes, int n_in,
                              void* d_out, int out_size, void* d_ws, size_t ws_size,
                              hipStream_t stream) {
    const float* X  = (const float*)d_in[0];
    const float* Wq = (const float*)d_in[1];
    const float* bq = (const float*)d_in[2];
    const float* Wk = (const float*)d_in[3];
    const float* bk = (const float*)d_in[4];
    const float* Wv = (const float*)d_in[5];
    const float* bv = (const float*)d_in[6];
    const float* Wo = (const float*)d_in[7];
    const float* bo = (const float*)d_in[8];
    float* out = (float*)d_out;

    if (ws_size < 80000000) return;
    char* ws = (char*)d_ws;
    unsigned short* Xb    = (unsigned short*)(ws);              // 16.78 MB; reused as AOb
    unsigned short* WqkvT = (unsigned short*)(ws + 16777216);   // [3072][2048] 12.58 MB
    unsigned short* WoT   = (unsigned short*)(ws + 29360128);   // 8.39 MB
    unsigned short* QKV   = (unsigned short*)(ws + 37748736);   // [4096][3072] 25.17 MB
    unsigned short* VbT   = (unsigned short*)(ws + 62914560);   // 4.19 MB
    unsigned short* part1 = (unsigned short*)(ws + 67108864);   // 512*64*128 bf16 = 8.39 MB
    float*          mlbuf = (float*)(ws + 75497472);            // 1024*64*2 f32 = 512 KB
    float*          bqkv  = (float*)(ws + 76021760);            // 12 KB
    unsigned short* AOb   = Xb;                                 // Xb dead after QKV GEMM

    k_cvt_bf16<<<(B_ * S_ * H_ / 4 + 255) / 256, 256, 0, stream>>>(X, Xb, B_ * S_ * H_ / 4);
    k_transpose_qkv<<<dim3(HQKV / 32, H_ / 32), dim3(32, 8), 0, stream>>>(Wq, Wk, Wv, WqkvT);
    k_transpose_cvt<<<dim3(H_ / 32, H_ / 32), dim3(32, 8), 0, stream>>>(Wo, WoT, H_, H_);
    k_concat_bias<<<(HQKV + 255) / 256, 256, 0, stream>>>(bq, bk, bv, bqkv);

    // fused QKV projection: [4096,2048] x [3072,2048]^T -> [4096,3072], Q cols pre-scaled
    k_gemm_bt<true, true><<<dim3(32 * 24), 256, 0, stream>>>(Xb, WqkvT, bqkv, QKV, 4096, HQKV, 2048, 32);

    k_transpose_v<<<dim3(KV_ / 32, S_ / 32, B_), dim3(32, 8), 0, stream>>>(QKV, VbT);
    k_flash<<<dim3(1536), 256, 0, stream>>>(QKV, VbT, AOb, part1, mlbuf);
    k_combine<<<dim3(512), 256, 0, stream>>>(mlbuf, part1, AOb);

    k_gemm_bt<false, false><<<dim3(32 * 16), 256, 0, stream>>>(AOb, WoT, bo, out, 4096, 2048, 2048, 32);
}

// Round 9
// 208.236 us; speedup vs baseline: 1.0735x; 1.0735x over previous
//
#include <hip/hip_runtime.h>

// Problem constants
#define B_   2
#define S_   2048
#define H_   2048
#define NH_  16
#define G_   4
#define HD_  128
#define KV_  512
#define HQKV 3072   // fused Q|K|V output width

typedef __attribute__((ext_vector_type(8))) short bf16x8;
typedef __attribute__((ext_vector_type(4))) float f32x4;

__device__ __forceinline__ unsigned short f2bf(float f) {
    unsigned u = __float_as_uint(f);
    u += 0x7fff + ((u >> 16) & 1);   // RNE
    return (unsigned short)(u >> 16);
}
__device__ __forceinline__ float bf2f(unsigned short s) {
    return __uint_as_float(((unsigned)s) << 16);
}
// D.lo = bf16(a), D.hi = bf16(b)  (RNE)
__device__ __forceinline__ unsigned cvtpk(float a, float b) {
    unsigned r;
    asm volatile("v_cvt_pk_bf16_f32 %0, %1, %2" : "=v"(r) : "v"(a), "v"(b));
    return r;
}

#define GLDS16(gsrc, ldst)                                                            \
    __builtin_amdgcn_global_load_lds(                                                 \
        (const __attribute__((address_space(1))) void*)(gsrc),                        \
        (__attribute__((address_space(3))) void*)(ldst), 16, 0, 0)

// 1/sqrt(128) * log2(e): folded into Q columns of the QKV GEMM epilogue
#define SC2F (0.08838834764831843f * 1.4426950408889634f)

// ---------------- fp32 -> bf16 elementwise ----------------
__global__ void k_cvt_bf16(const float* __restrict__ in, unsigned short* __restrict__ out, int n4) {
    int i = blockIdx.x * blockDim.x + threadIdx.x;
    if (i >= n4) return;
    float4 v = ((const float4*)in)[i];
    ushort4 o;
    o.x = f2bf(v.x); o.y = f2bf(v.y); o.z = f2bf(v.z); o.w = f2bf(v.w);
    ((ushort4*)out)[i] = o;
}

// ---------------- fp32 [R][C] -> bf16 [C][R] (weight transpose+convert) ----------------
__global__ void k_transpose_cvt(const float* __restrict__ in, unsigned short* __restrict__ out,
                                int R, int C) {
    __shared__ float t[32][33];
    int c0 = blockIdx.x * 32, r0 = blockIdx.y * 32;
    int tx = threadIdx.x, ty = threadIdx.y;   // 32 x 8
#pragma unroll
    for (int i = 0; i < 4; ++i)
        t[ty + i*8][tx] = in[(size_t)(r0 + ty + i*8) * C + c0 + tx];
    __syncthreads();
#pragma unroll
    for (int i = 0; i < 4; ++i)
        out[(size_t)(c0 + ty + i*8) * R + r0 + tx] = f2bf(t[tx][ty + i*8]);
}

// ---------------- fused Wq|Wk|Wv transpose+convert -> WqkvT [3072][2048] ----------------
__global__ void k_transpose_qkv(const float* __restrict__ Wq, const float* __restrict__ Wk,
                                const float* __restrict__ Wv, unsigned short* __restrict__ out) {
    __shared__ float t[32][33];
    int n0g = blockIdx.x * 32;               // output row block (0..3071)
    int h0 = blockIdx.y * 32;                // input row block (0..2047)
    const float* src; int C, n0l;
    if (n0g < H_)            { src = Wq; C = H_;  n0l = n0g; }
    else if (n0g < H_ + KV_) { src = Wk; C = KV_; n0l = n0g - H_; }
    else                     { src = Wv; C = KV_; n0l = n0g - H_ - KV_; }
    int tx = threadIdx.x, ty = threadIdx.y;  // 32 x 8
#pragma unroll
    for (int i = 0; i < 4; ++i)
        t[ty + i*8][tx] = src[(size_t)(h0 + ty + i*8) * C + n0l + tx];
    __syncthreads();
#pragma unroll
    for (int i = 0; i < 4; ++i)
        out[(size_t)(n0g + ty + i*8) * H_ + h0 + tx] = f2bf(t[tx][ty + i*8]);
}

// ---------------- concat bq|bk|bv -> [3072] ----------------
__global__ void k_concat_bias(const float* __restrict__ bq, const float* __restrict__ bk,
                              const float* __restrict__ bv, float* __restrict__ out) {
    int i = blockIdx.x * 256 + threadIdx.x;
    if (i >= HQKV) return;
    out[i] = (i < H_) ? bq[i] : (i < H_ + KV_ ? bk[i - H_] : bv[i - H_ - KV_]);
}

// ---------------- V slice of QKV [B*S][3072] -> V^T [B][KV][S] ----------------
__global__ void k_transpose_v(const unsigned short* __restrict__ in, unsigned short* __restrict__ out) {
    __shared__ unsigned short t[32][33];
    int b = blockIdx.z;
    int c0 = blockIdx.x * 32, s0 = blockIdx.y * 32;
    int tx = threadIdx.x, ty = threadIdx.y;
#pragma unroll
    for (int i = 0; i < 4; ++i)
        t[ty + i*8][tx] = in[((size_t)b * S_ + s0 + ty + i*8) * HQKV + (H_ + KV_) + c0 + tx];
    __syncthreads();
#pragma unroll
    for (int i = 0; i < 4; ++i)
        out[((size_t)b * KV_ + c0 + ty + i*8) * S_ + s0 + tx] = t[tx][ty + i*8];
}

// ---------------- 256x256 8-phase bf16 GEMM (HK-template port) ----------------
// 512 threads = 8 waves (2 wave-rows x 4 wave-cols), per-wave C = 128x64.
// BK=64, double-buffered 128 KB LDS. Per K-tile: 4 phases, each = {ds_read subtile,
// stage 1 half-tile (row-stripe) of a future tile, barrier, lgkmcnt(0), 16 MFMA,
// barrier}. Stage-halves are ROW-STRIPES aligned to the phase structure:
//   A stripe h = rows with bit6==h (read only in phases mh==h)
//   B stripe h = rows with bit5==h (read only in phases nh==h)
// Stage schedule per tile t (phases q0..q3 = (nh,mh) = 00,01,10,11):
//   q0: B-s1(t+1)  q1: A-s1(t+1)  q2: B-s0(t+2)  q3: A-s0(t+2)
// Each target region's last read is >=1 barrier before the stage issue.
// vmcnt ledger: tile-top vmcnt(4) retires tile t fully (2 half-tiles of t+1/t+2
// in flight); last tile vmcnt(0). Prologue issues: Bs0(0) As0(0) Bs1(0) As1(0)
// Bs0(1) As0(1) = 12 loads.
template <bool BF16OUT, bool QSCALE>
__global__ __launch_bounds__(512, 2) void k_gemm256(
    const unsigned short* __restrict__ A, const unsigned short* __restrict__ Bt,
    const float* __restrict__ bias, void* __restrict__ Cout, int M, int N, int K) {
    __shared__ __align__(16) unsigned short As[2][256 * 64];
    __shared__ __align__(16) unsigned short Bs[2][256 * 64];
    const int tid = threadIdx.x, lane = tid & 63;
    const int w = tid >> 6;
    const int l15 = lane & 15, l4 = lane >> 4;
    const int wr = w >> 2, wc = w & 3;        // 2 x 4 wave grid
    const int m0 = blockIdx.x * 256, n0 = blockIdx.y * 256;
    f32x4 acc[8][4] = {};

    // stage one row-stripe (128 rows) of A: rows with ((row>>6)&1)==h
    auto stageA = [&](int buf, int kt, int h) {
#pragma unroll
        for (int i = 0; i < 2; ++i) {
            int p = i * 512 + tid;            // 0..1023
            int j = p >> 3;                   // 0..127 stripe-row index
            int row = h * 64 + (j >> 6) * 128 + (j & 63);
            int sc = p & 7;
            int c = sc ^ (row & 7);
            GLDS16(A + (size_t)(m0 + row) * K + kt * 64 + c * 8,
                   &As[buf][(row * 8 + sc) * 8]);
        }
    };
    // stage one row-stripe of B: rows with ((row>>5)&1)==h
    auto stageB = [&](int buf, int kt, int h) {
#pragma unroll
        for (int i = 0; i < 2; ++i) {
            int p = i * 512 + tid;
            int j = p >> 3;
            int row = h * 32 + (j >> 5) * 64 + (j & 31);
            int sc = p & 7;
            int c = sc ^ (row & 7);
            GLDS16(Bt + (size_t)(n0 + row) * K + kt * 64 + c * 8,
                   &Bs[buf][(row * 8 + sc) * 8]);
        }
    };

    const int NT = K >> 6;    // 32 for K=2048
    // prologue (issue order defines the vmcnt ledger)
    stageB(0, 0, 0); stageA(0, 0, 0); stageB(0, 0, 1); stageA(0, 0, 1);
    stageB(1, 1, 0); stageA(1, 1, 0);

    bf16x8 bf[2][2];   // B-frags persist q0->q1 and q2->q3
    for (int t = 0; t < NT; ++t) {
        const int cur = t & 1, nxt = cur ^ 1;
        if (t == NT - 1) { asm volatile("s_waitcnt vmcnt(0)" ::: "memory"); }
        else             { asm volatile("s_waitcnt vmcnt(4)" ::: "memory"); }
        __builtin_amdgcn_s_barrier();          // tile t fully in LDS for all waves
        __builtin_amdgcn_sched_barrier(0);

#pragma unroll
        for (int q = 0; q < 4; ++q) {
            const int nh = q >> 1, mh = q & 1;
            // register subtile loads (A: 8 reads; B: 4 reads on mh==0 phases)
            bf16x8 af[4][2];
#pragma unroll
            for (int mf2 = 0; mf2 < 4; ++mf2)
#pragma unroll
                for (int ks = 0; ks < 2; ++ks) {
                    int row = wr * 128 + (mh * 4 + mf2) * 16 + l15;
                    int ch = (ks * 4 + l4) ^ (row & 7);
                    af[mf2][ks] = *(const bf16x8*)(&As[cur][(row * 8 + ch) * 8]);
                }
            if (mh == 0) {
#pragma unroll
                for (int nf2 = 0; nf2 < 2; ++nf2)
#pragma unroll
                    for (int ks = 0; ks < 2; ++ks) {
                        int row = wc * 64 + (nh * 2 + nf2) * 16 + l15;
                        int ch = (ks * 4 + l4) ^ (row & 7);
                        bf[nf2][ks] = *(const bf16x8*)(&Bs[cur][(row * 8 + ch) * 8]);
                    }
            }
            // half-tile prefetch (targets freed >=1 barrier ago)
            if (q == 0)      { if (t + 1 < NT) stageB(nxt, t + 1, 1); }
            else if (q == 1) { if (t + 1 < NT) stageA(nxt, t + 1, 1); }
            else if (q == 2) { if (t + 2 < NT) stageB(cur, t + 2, 0); }
            else             { if (t + 2 < NT) stageA(cur, t + 2, 0); }

            __builtin_amdgcn_sched_barrier(0);
            __builtin_amdgcn_s_barrier();
            asm volatile("s_waitcnt lgkmcnt(0)" ::: "memory");
            __builtin_amdgcn_sched_barrier(0);
            __builtin_amdgcn_s_setprio(1);
#pragma unroll
            for (int mf2 = 0; mf2 < 4; ++mf2)
#pragma unroll
                for (int nf2 = 0; nf2 < 2; ++nf2)
#pragma unroll
                    for (int ks = 0; ks < 2; ++ks)
                        acc[mh * 4 + mf2][nh * 2 + nf2] = __builtin_amdgcn_mfma_f32_16x16x32_bf16(
                            af[mf2][ks], bf[nf2][ks], acc[mh * 4 + mf2][nh * 2 + nf2], 0, 0, 0);
            __builtin_amdgcn_s_setprio(0);
            __builtin_amdgcn_s_barrier();
        }
    }

    // epilogue
#pragma unroll
    for (int mf = 0; mf < 8; ++mf) {
        int row = m0 + wr * 128 + mf * 16 + l4 * 4;
#pragma unroll
        for (int nf = 0; nf < 4; ++nf) {
            int col = n0 + wc * 64 + nf * 16 + l15;
            float bv = bias[col];
#pragma unroll
            for (int r = 0; r < 4; ++r) {
                float v = acc[mf][nf][r] + bv;
                if (QSCALE) { if (col < H_) v *= SC2F; }
                if (BF16OUT)
                    ((unsigned short*)Cout)[(size_t)(row + r) * N + col] = f2bf(v);
                else
                    ((float*)Cout)[(size_t)(row + r) * N + col] = v;
            }
        }
    }
}

// ---------------- 128x128 2-phase bf16 GEMM (R7-proven, for O-proj) ----------------
template <bool BF16OUT, bool QSCALE>
__global__ __launch_bounds__(256) void k_gemm_bt(
    const unsigned short* __restrict__ A, const unsigned short* __restrict__ Bt,
    const float* __restrict__ bias, void* __restrict__ Cout, int M, int N, int K) {
    __shared__ __align__(16) unsigned short As[128 * 64];
    __shared__ __align__(16) unsigned short Bs[128 * 64];
    const int tid = threadIdx.x, lane = tid & 63, w = tid >> 6;
    const int l15 = lane & 15, l4 = lane >> 4;
    const int wr = w >> 1, wc = w & 1;
    const int m0 = blockIdx.x * 128, n0 = blockIdx.y * 128;
    f32x4 acc[4][4] = {};

    for (int kt = 0; kt < K; kt += 64) {
        __syncthreads();
#pragma unroll
        for (int i = 0; i < 4; ++i) {
            int p = (w * 4 + i) * 64 + lane;
            int row = p >> 3, c = (p & 7) ^ (row & 7);
            GLDS16(A + (size_t)(m0 + row) * K + kt + c * 8, As + (size_t)(w * 4 + i) * 512);
        }
#pragma unroll
        for (int i = 0; i < 4; ++i) {
            int p = (w * 4 + i) * 64 + lane;
            int row = p >> 3, c = (p & 7) ^ (row & 7);
            GLDS16(Bt + (size_t)(n0 + row) * K + kt + c * 8, Bs + (size_t)(w * 4 + i) * 512);
        }
        __syncthreads();
#pragma unroll
        for (int ks = 0; ks < 2; ++ks) {
            bf16x8 af[4], bfr[4];
#pragma unroll
            for (int m = 0; m < 4; ++m) {
                int row = wr * 64 + m * 16 + l15;
                int ch = (ks * 4 + l4) ^ (row & 7);
                af[m] = *(const bf16x8*)(As + row * 64 + ch * 8);
            }
#pragma unroll
            for (int n = 0; n < 4; ++n) {
                int row = wc * 64 + n * 16 + l15;
                int ch = (ks * 4 + l4) ^ (row & 7);
                bfr[n] = *(const bf16x8*)(Bs + row * 64 + ch * 8);
            }
#pragma unroll
            for (int m = 0; m < 4; ++m)
#pragma unroll
                for (int n = 0; n < 4; ++n)
                    acc[m][n] = __builtin_amdgcn_mfma_f32_16x16x32_bf16(af[m], bfr[n], acc[m][n], 0, 0, 0);
        }
    }
#pragma unroll
    for (int m = 0; m < 4; ++m) {
        int row = m0 + wr * 64 + m * 16 + l4 * 4;
#pragma unroll
        for (int n = 0; n < 4; ++n) {
            int col = n0 + wc * 64 + n * 16 + l15;
            float bv = bias[col];
#pragma unroll
            for (int r = 0; r < 4; ++r) {
                float v = acc[m][n][r] + bv;
                if (QSCALE) { if (col < H_) v *= SC2F; }
                if (BF16OUT)
                    ((unsigned short*)Cout)[(size_t)(row + r) * N + col] = f2bf(v);
                else
                    ((float*)Cout)[(size_t)(row + r) * N + col] = v;
            }
        }
    }
}

// ---------------- causal GQA flash attention: swapped-QK, in-register softmax ----------------
__global__ __launch_bounds__(256, 4) void k_flash(
    const unsigned short* __restrict__ QKV,  // [B*S][3072]  Q|K|V  (Q pre-scaled)
    const unsigned short* __restrict__ VT,   // [B][KV][S]
    unsigned short* __restrict__ Oa,         // [B*S][H]
    unsigned short* __restrict__ part1,      // [512][64][128] bf16 chunk1 partial O
    float* __restrict__ mlbuf) {             // [1024][64][2] f32 (m,l) per chunk
    __shared__ __align__(16) unsigned short Ks[64 * 128];    // K tile, chunk-swizzled
    __shared__ __align__(16) unsigned short Vs[128 * 64];    // V^T tile, chunk-swizzled
    const int tid = threadIdx.x, lane = tid & 63, w = tid >> 6;
    const int l15 = lane & 15, l4 = lane >> 4;
    const int bid = blockIdx.x;               // 0..1535
    const int xcd = bid & 7, idx = bid >> 3;  // 192 jobs per XCD
    const int bh = xcd * 4 + (idx & 3);       // 4 heads per XCD = one (b,g)
    const int jidx = idx >> 2;                // 0..47, descending work
    const int b = bh >> 4, nh = bh & 15, g = nh >> 2;

    int qt, t0, t1, mode;                     // mode: 0 full, 1 chunk0, 2 chunk1
    if (jidx < 16) { qt = 16 + jidx; t0 = 0; t1 = 16; mode = 1; }
    else {
        int k = jidx - 16, j = k >> 1;
        if ((k & 1) == 0) { qt = 31 - j; t0 = 16; t1 = qt + 1; mode = 2; }
        else              { qt = 15 - j; t0 = 0;  t1 = qt + 1; mode = 0; }
    }
    const int qbase = qt * 64 + w * 16;       // wave's 16 q-rows; lane's q = qbase + l15

    const unsigned short* kgbase = QKV + (size_t)b * S_ * HQKV + H_ + g * HD_;
    const unsigned short* vgbase = VT + ((size_t)b * KV_ + g * HD_) * S_;

    auto issueK = [&](int kt) {
        const int kv0 = kt * 64;
#pragma unroll
        for (int i = 0; i < 4; ++i) {
            int p = i * 256 + tid;
            int row = p >> 4, c = (p & 15) ^ (row & 15);
            GLDS16(kgbase + (size_t)(kv0 + row) * HQKV + c * 8, &Ks[(i * 256 + w * 64) * 8]);
        }
    };
    auto issueV = [&](int kt) {
        const int kv0 = kt * 64;
#pragma unroll
        for (int i = 0; i < 4; ++i) {
            int p = i * 256 + tid;
            int row = p >> 3, c = (p & 7) ^ (row & 7);
            GLDS16(vgbase + (size_t)row * S_ + kv0 + c * 8, &Vs[(i * 256 + w * 64) * 8]);
        }
    };

    bf16x8 qf[4];
#pragma unroll
    for (int kb = 0; kb < 4; ++kb)
        qf[kb] = *(const bf16x8*)(QKV + (size_t)(b * S_ + qbase + l15) * HQKV +
                                  nh * HD_ + kb * 32 + l4 * 8);

    f32x4 o[8] = {};                          // O^T: o[nc][r] = O[d=nc*16+l4*4+r][q=l15]
    float m_r = -1e30f, l_r = 0.f;

    const int src0 = l15 + 16 * ((2 * l4) & 3);
    const int src1 = l15 + 16 * ((2 * l4 + 1) & 3);
    const bool hsel = ((l4 >> 1) & 1) != 0;

    issueK(t0);
    issueV(t0);

    for (int kt = t0; kt < t1; ++kt) {
        const int kv0 = kt * 64;
        asm volatile("s_waitcnt vmcnt(4)" ::: "memory");
        __builtin_amdgcn_s_barrier();
        __builtin_amdgcn_sched_barrier(0);

        // S^T = K Q^T
        f32x4 s[4] = {};
#pragma unroll
        for (int kb = 0; kb < 4; ++kb) {
            bf16x8 kf[4];
#pragma unroll
            for (int n = 0; n < 4; ++n) {
                int row = n * 16 + l15;
                int sl = (kb * 4 + l4) ^ (row & 15);
                kf[n] = *(const bf16x8*)(&Ks[(row * 16 + sl) * 8]);
            }
            __builtin_amdgcn_s_setprio(1);
#pragma unroll
            for (int n = 0; n < 4; ++n)
                s[n] = __builtin_amdgcn_mfma_f32_16x16x32_bf16(kf[n], qf[kb], s[n], 0, 0, 0);
            __builtin_amdgcn_s_setprio(0);
        }
        if (kv0 + 63 > qbase) {
            const int qrow = qbase + l15;
#pragma unroll
            for (int n = 0; n < 4; ++n)
#pragma unroll
                for (int r = 0; r < 4; ++r) {
                    int kcol = kv0 + n * 16 + l4 * 4 + r;
                    if (kcol > qrow) s[n][r] = -1e30f;
                }
        }
        float pmax = s[0][0];
#pragma unroll
        for (int n = 0; n < 4; ++n)
#pragma unroll
            for (int r = 0; r < 4; ++r) pmax = fmaxf(pmax, s[n][r]);
        pmax = fmaxf(pmax, __shfl_xor(pmax, 16));
        pmax = fmaxf(pmax, __shfl_xor(pmax, 32));
        if (__any(pmax > m_r + 8.0f)) {
            float mn = fmaxf(m_r, pmax);
            float sf = exp2f(m_r - mn);
            m_r = mn;
            l_r *= sf;
#pragma unroll
            for (int nc = 0; nc < 8; ++nc) {
                f32x4 t = o[nc];
                t[0] *= sf; t[1] *= sf; t[2] *= sf; t[3] *= sf;
                o[nc] = t;
            }
        }
        float rsum = 0.f;
#pragma unroll
        for (int n = 0; n < 4; ++n)
#pragma unroll
            for (int r = 0; r < 4; ++r) {
                float p = exp2f(s[n][r] - m_r);
                s[n][r] = p;
                rsum += p;
            }
        rsum += __shfl_xor(rsum, 16);
        rsum += __shfl_xor(rsum, 32);
        l_r += rsum;

        unsigned plo[4], phi[4];
#pragma unroll
        for (int n = 0; n < 4; ++n) {
            plo[n] = cvtpk(s[n][0], s[n][1]);
            phi[n] = cvtpk(s[n][2], s[n][3]);
        }

        asm volatile("s_waitcnt vmcnt(0)" ::: "memory");
        __builtin_amdgcn_s_barrier();
        __builtin_amdgcn_sched_barrier(0);
        if (kt + 1 < t1) issueK(kt + 1);

#pragma unroll
        for (int kb = 0; kb < 2; ++kb) {
            const int n0i = 2 * kb, n1i = 2 * kb + 1;
            unsigned a0, a1, w0, w1, w2, w3;
            a0 = __shfl((int)plo[n0i], src0); a1 = __shfl((int)plo[n1i], src0); w0 = hsel ? a1 : a0;
            a0 = __shfl((int)phi[n0i], src0); a1 = __shfl((int)phi[n1i], src0); w1 = hsel ? a1 : a0;
            a0 = __shfl((int)plo[n0i], src1); a1 = __shfl((int)plo[n1i], src1); w2 = hsel ? a1 : a0;
            a0 = __shfl((int)phi[n0i], src1); a1 = __shfl((int)phi[n1i], src1); w3 = hsel ? a1 : a0;
            int4 pw = make_int4((int)w0, (int)w1, (int)w2, (int)w3);
            bf16x8 pf = *(bf16x8*)&pw;
            __builtin_amdgcn_s_setprio(1);
#pragma unroll
            for (int nc = 0; nc < 8; ++nc) {
                int row = nc * 16 + l15;
                int sl = (kb * 4 + l4) ^ (row & 7);
                bf16x8 vf = *(const bf16x8*)(&Vs[(row * 8 + sl) * 8]);
                o[nc] = __builtin_amdgcn_mfma_f32_16x16x32_bf16(vf, pf, o[nc], 0, 0, 0);
            }
            __builtin_amdgcn_s_setprio(0);
        }

        __builtin_amdgcn_s_barrier();
        __builtin_amdgcn_sched_barrier(0);
        if (kt + 1 < t1) issueV(kt + 1);
    }

    const int qrow = qbase + l15;
    if (mode == 0) {
        float inv = 1.0f / l_r;
        size_t base = (size_t)(b * S_ + qrow) * H_ + nh * HD_ + l4 * 4;
#pragma unroll
        for (int nc = 0; nc < 8; ++nc) {
            uint2 pk;
            pk.x = cvtpk(o[nc][0] * inv, o[nc][1] * inv);
            pk.y = cvtpk(o[nc][2] * inv, o[nc][3] * inv);
            *(uint2*)(Oa + base + nc * 16) = pk;
        }
    } else {
        const int base = bh * 16 + (qt - 16);
        const int c = (mode == 1) ? 0 : 1;
        float* mlrec = mlbuf + (size_t)(base * 2 + c) * 64 * 2;
        if (l4 == 0) {
            int row = w * 16 + l15;
            mlrec[row * 2 + 0] = m_r;
            mlrec[row * 2 + 1] = l_r;
        }
        if (mode == 1) {
            size_t ob = (size_t)(b * S_ + qrow) * H_ + nh * HD_ + l4 * 4;
#pragma unroll
            for (int nc = 0; nc < 8; ++nc) {
                uint2 pk;
                pk.x = cvtpk(o[nc][0], o[nc][1]);
                pk.y = cvtpk(o[nc][2], o[nc][3]);
                *(uint2*)(Oa + ob + nc * 16) = pk;
            }
        } else {
            size_t pb = ((size_t)base * 64 + w * 16 + l15) * 128 + l4 * 4;
#pragma unroll
            for (int nc = 0; nc < 8; ++nc) {
                uint2 pk;
                pk.x = cvtpk(o[nc][0], o[nc][1]);
                pk.y = cvtpk(o[nc][2], o[nc][3]);
                *(uint2*)(part1 + pb + nc * 16) = pk;
            }
        }
    }
}

// ---------------- combine split-K partials ----------------
__global__ __launch_bounds__(256) void k_combine(
    const float* __restrict__ mlbuf, const unsigned short* __restrict__ part1,
    unsigned short* __restrict__ Oa) {
    int rec = blockIdx.x;                 // 0..511: bh*16 + (qt-16)
    int bh = rec >> 4, qt = 16 + (rec & 15);
    int b = bh >> 4, nh = bh & 15;
    int row = threadIdx.x >> 2;           // 0..63
    int dseg = (threadIdx.x & 3) * 32;
    const float* ml0 = mlbuf + (size_t)(rec * 2 + 0) * 128;
    const float* ml1 = mlbuf + (size_t)(rec * 2 + 1) * 128;
    float m0 = ml0[row * 2], l0 = ml0[row * 2 + 1];
    float m1 = ml1[row * 2], l1 = ml1[row * 2 + 1];
    float M = fmaxf(m0, m1);
    float a0 = exp2f(m0 - M), a1 = exp2f(m1 - M);
    float L = a0 * l0 + a1 * l1;
    float s0 = a0 / L, s1 = a1 / L;
    size_t ob = ((size_t)(b * S_) + qt * 64 + row) * H_ + nh * HD_ + dseg;
    const unsigned short* p1 = part1 + ((size_t)rec * 64 + row) * 128 + dseg;
#pragma unroll
    for (int i = 0; i < 4; ++i) {
        bf16x8 v0 = *(const bf16x8*)(Oa + ob + i * 8);
        bf16x8 v1 = *(const bf16x8*)(p1 + i * 8);
        bf16x8 oo;
#pragma unroll
        for (int e = 0; e < 8; ++e)
            oo[e] = (short)f2bf(bf2f((unsigned short)v0[e]) * s0 +
                                bf2f((unsigned short)v1[e]) * s1);
        *(bf16x8*)(Oa + ob + i * 8) = oo;
    }
}

// ---------------- launch ----------------
extern "C" void kernel_launch(void* const* d_in, const int* in_sizes, int n_in,
                              void* d_out, int out_size, void* d_ws, size_t ws_size,
                              hipStream_t stream) {
    const float* X  = (const float*)d_in[0];
    const float* Wq = (const float*)d_in[1];
    const float* bq = (const float*)d_in[2];
    const float* Wk = (const float*)d_in[3];
    const float* bk = (const float*)d_in[4];
    const float* Wv = (const float*)d_in[5];
    const float* bv = (const float*)d_in[6];
    const float* Wo = (const float*)d_in[7];
    const float* bo = (const float*)d_in[8];
    float* out = (float*)d_out;

    if (ws_size < 80000000) return;
    char* ws = (char*)d_ws;
    unsigned short* Xb    = (unsigned short*)(ws);              // 16.78 MB; reused as AOb
    unsigned short* WqkvT = (unsigned short*)(ws + 16777216);   // [3072][2048] 12.58 MB
    unsigned short* WoT   = (unsigned short*)(ws + 29360128);   // 8.39 MB
    unsigned short* QKV   = (unsigned short*)(ws + 37748736);   // [4096][3072] 25.17 MB
    unsigned short* VbT   = (unsigned short*)(ws + 62914560);   // 4.19 MB
    unsigned short* part1 = (unsigned short*)(ws + 67108864);   // 512*64*128 bf16 = 8.39 MB
    float*          mlbuf = (float*)(ws + 75497472);            // 1024*64*2 f32 = 512 KB
    float*          bqkv  = (float*)(ws + 76021760);            // 12 KB
    unsigned short* AOb   = Xb;                                 // Xb dead after QKV GEMM

    k_cvt_bf16<<<(B_ * S_ * H_ / 4 + 255) / 256, 256, 0, stream>>>(X, Xb, B_ * S_ * H_ / 4);
    k_transpose_qkv<<<dim3(HQKV / 32, H_ / 32), dim3(32, 8), 0, stream>>>(Wq, Wk, Wv, WqkvT);
    k_transpose_cvt<<<dim3(H_ / 32, H_ / 32), dim3(32, 8), 0, stream>>>(Wo, WoT, H_, H_);
    k_concat_bias<<<(HQKV + 255) / 256, 256, 0, stream>>>(bq, bk, bv, bqkv);

    // fused QKV projection: 256^2 8-phase, grid 16x12 = 192 blocks
    k_gemm256<true, true><<<dim3(16, 12), 512, 0, stream>>>(Xb, WqkvT, bqkv, QKV, 4096, HQKV, 2048);

    k_transpose_v<<<dim3(KV_ / 32, S_ / 32, B_), dim3(32, 8), 0, stream>>>(QKV, VbT);
    k_flash<<<dim3(1536), 256, 0, stream>>>(QKV, VbT, AOb, part1, mlbuf);
    k_combine<<<dim3(512), 256, 0, stream>>>(mlbuf, part1, AOb);

    // O-projection: proven 128^2 2-phase
    k_gemm_bt<false, false><<<dim3(32, 16), 256, 0, stream>>>(AOb, WoT, bo, out, 4096, 2048, 2048);
}